// Round 4
// baseline (204.635 us; speedup 1.0000x reference)
//
#include <hip/hip_runtime.h>
#include <cmath>

// CXLoss pipeline, revision 22: S ELIMINATED — 3 fused GEMM sweeps.
// R21 evidence: k_gemm9 write 132.6MB/51.2us = 2.59 TB/s = pure-write
// roofline; barrier restructure changed nothing (51.2 -> 51.2). pass1/pass2
// (each re-reading 134MB S) explain the stubborn ~125us non-gemm block.
// => the whole pipeline was S-traffic-bound (402MB). Fix: recompute the
// 34-GFLOP GEMM 3x (MFMA deterministic => bit-identical acc across sweeps):
//   k_gA: GEMM + colmax partials (no store)
//   k_gB: GEMM + Wsum partials (a,b derived per-lane from CMAX)
//   k_gC: GEMM + maxv via LDS-transpose row-max over 128-q strip
// Full fp32 everywhere (bf16 S rounding dropped — strictly closer to ref).

#define NB 4
#define CC 256
#define HW 4096
#define NQ0 8    // p-slab loop-split (CMAX/WSUM partials)
#define NCS 32   // q col-strips (MAXP partials)

static constexpr float kEPS = 1e-8f;
static constexpr float kSIG = 0.1f + 1e-8f;

typedef __attribute__((ext_vector_type(8)))  short short8;
typedef __attribute__((ext_vector_type(16))) float f32x16;

// workspace layout (float units)
enum {
  OFF_MEAN = 0,                        // 256 channel means
  OFF_CMAX = 256,                      // NQ0*NB*HW colmax partials
  OFF_WSUM = OFF_CMAX + NQ0*NB*HW,     // NQ0*NB*HW Wsum partials
  OFF_MAXP = OFF_WSUM + NQ0*NB*HW,     // NCS*NB*HW maxv partials (2MB)
  OFF_MAXV = OFF_MAXP + NCS*NB*HW,     // NB*HW maxv
  OFF_GB   = OFF_MAXV + NB*HW,         // gamma[NB*HW], beta[NB*HW]
  OFF_GT   = OFF_GB + 2*NB*HW,         // NB*HW*CC bf16, fragment-tiled
  OFF_GI   = OFF_GT + NB*HW*CC/2,
  WS_FLOATS_FULL = OFF_GI + NB*HW*CC/2
};

__device__ __forceinline__ ushort cvt_bf16(float x) {
  unsigned u = __float_as_uint(x);
  unsigned r = (u + 0x7fffu + ((u >> 16) & 1u)) >> 16;  // round-nearest-even
  return (ushort)r;
}
__device__ __forceinline__ float bf2f(ushort u) {
  return __uint_as_float((unsigned)u << 16);
}

__device__ __forceinline__ float blockSum256(float v) {
  __shared__ float sh[4];
  const int lane = threadIdx.x & 63, wv = threadIdx.x >> 6;
  #pragma unroll
  for (int o = 32; o > 0; o >>= 1) v += __shfl_down(v, o, 64);
  __syncthreads();
  if (lane == 0) sh[wv] = v;
  __syncthreads();
  return sh[0] + sh[1] + sh[2] + sh[3];
}

// K1: per-channel mean of featureT. grid=256
__global__ __launch_bounds__(256) void k_mean9(const float* __restrict__ fT,
                                               float* __restrict__ ws) {
  const int c = blockIdx.x, t = threadIdx.x;
  float s = 0.f;
  for (int n = 0; n < NB; ++n) {
    const float* p = fT + (size_t)(n*CC + c)*HW;
    #pragma unroll
    for (int k = 0; k < 16; ++k) s += p[k*256 + t];
  }
  const float tot = blockSum256(s);
  if (t == 0) ws[OFF_MEAN + c] = tot * (1.0f/16384.0f);
}

// K2: fused normalize + fragment-tiled bf16 write (verified R14 layout):
// offset_ushort(n, r32, kc) = ((n*128 + r32)*16 + kc)*512 + l*8
//   holds X[n][p = r32*32 + (l&31)][c = kc*16 + (l>>5)*8 + j], j<8.
// grid = 2 * NB * 128 = 1024 blocks.
__global__ __launch_bounds__(256) void k_prep9(const float* __restrict__ fT,
                                               const float* __restrict__ fI,
                                               float* __restrict__ ws) {
  __shared__ float stage[32][257];
  __shared__ float prt[8][32];
  __shared__ float sinv[32];
  const int t = threadIdx.x, l = t & 63;
  int bid = blockIdx.x;
  const int tensor = (bid >= 512); bid &= 511;
  const int n   = bid >> 7;
  const int r32 = bid & 127;
  const int p0  = r32 * 32;

  const float* __restrict__ src = tensor ? fI : fT;
  ushort* __restrict__ dst = (ushort*)(ws + (tensor ? OFF_GI : OFF_GT));
  const float* __restrict__ mean = ws + OFF_MEAN;

  const int pl = t & 31, cg = t >> 5;
  float acc = 0.f;
  #pragma unroll
  for (int i = 0; i < 32; ++i) {
    const int c = cg*32 + i;
    const float v = src[((size_t)(n*CC + c))*HW + p0 + pl] - mean[c];
    stage[pl][c] = v;
    acc += v*v;
  }
  prt[cg][pl] = acc;
  __syncthreads();
  if (t < 32) {
    float s = 0.f;
    #pragma unroll
    for (int g = 0; g < 8; ++g) s += prt[g][t];
    sinv[t] = 1.0f/(sqrtf(s) + kEPS);
  }
  __syncthreads();

  const int w = t >> 6, lhi = l >> 5, m = l & 31;
  const float iv = sinv[m];
  #pragma unroll
  for (int i = 0; i < 4; ++i) {
    const int kc = w*4 + i;
    const int cb = kc*16 + lhi*8;
    short8 o;
    #pragma unroll
    for (int j = 0; j < 8; ++j)
      ((ushort*)&o)[j] = cvt_bf16(stage[m][cb + j] * iv);
    *(short8*)(dst + (((size_t)(n*128 + r32)*16 + kc) << 9) + l*8) = o;
  }
}

// ---- shared GEMM-sweep geometry ----
// block b: h = b&7 (p-slab of 512), sid = b>>3; n = sid>>5, col0 = (sid&31)*128.
// wave w owns q col-tile col0+w*32; lane's q = col0 + w*32 + (l&31).
// per iter: Ab <- 32 p-rows; 16 MFMA (kc) -> acc[16];
// C/D map: col(q) = lane&31, row(p) = (r&3) + 8*(r>>2) + 4*(lane>>5).

// K3a: GEMM sweep + colmax partials. grid 1024, 4 blocks/CU.
__global__ __launch_bounds__(256, 4) void k_gA(
    const ushort* __restrict__ gA, const ushort* __restrict__ gB,
    float* __restrict__ ws)
{
  __shared__ ushort Ab[8192];
  __shared__ float red2[128];

  const int t = threadIdx.x;
  const int w = t >> 6, l = t & 63;
  const int ln31 = l & 31;

  const int b = blockIdx.x;
  const int h = b & 7, sid = b >> 3;
  const int n = sid >> 5;
  const int col0 = (sid & 31) * 128;

  const ushort* __restrict__ gAn = gA + (size_t)(n*128 + h*16)*8192;

  short8 pf[4];
  #pragma unroll
  for (int i = 0; i < 4; ++i)
    pf[i] = *(const short8*)(gAn + (size_t)(i*256 + t)*8);

  const int RB = (col0 >> 5) + w;
  short8 breg[16];
  #pragma unroll
  for (int kc = 0; kc < 16; ++kc)
    breg[kc] = *(const short8*)(gB +
        (((size_t)(n*128 + RB)*16 + kc) << 9) + l*8);

  float runl = -3.0e38f;

  for (int iter = 0; iter < 16; ++iter) {
    __syncthreads();
    #pragma unroll
    for (int i = 0; i < 4; ++i)
      *(short8*)&Ab[(i*256 + t)*8] = pf[i];
    __syncthreads();
    if (iter + 1 < 16) {
      const ushort* __restrict__ src = gAn + (size_t)(iter + 1)*8192;
      #pragma unroll
      for (int i = 0; i < 4; ++i)
        pf[i] = *(const short8*)(src + (size_t)(i*256 + t)*8);
    }

    f32x16 acc;
    #pragma unroll
    for (int e = 0; e < 16; ++e) acc[e] = 0.f;
    #pragma unroll
    for (int kc = 0; kc < 16; ++kc) {
      const short8 a0 = *(const short8*)&Ab[kc*512 + l*8];
      acc = __builtin_amdgcn_mfma_f32_32x32x16_bf16(a0, breg[kc], acc, 0, 0, 0);
    }
    #pragma unroll
    for (int r = 0; r < 16; ++r) runl = fmaxf(runl, acc[r]);
  }

  runl = fmaxf(runl, __shfl_xor(runl, 32, 64));
  if (l < 32) red2[w*32 + ln31] = runl;
  __syncthreads();
  if (t < 128)
    ws[OFF_CMAX + h*(NB*HW) + n*HW + col0 + t] = red2[t];
}

// K3b: GEMM sweep + Wsum partials. Per-lane a,b derived from CMAX.
__global__ __launch_bounds__(256, 4) void k_gB(
    const ushort* __restrict__ gA, const ushort* __restrict__ gB,
    float* __restrict__ ws)
{
  __shared__ ushort Ab[8192];
  __shared__ float red2[128];

  const int t = threadIdx.x;
  const int w = t >> 6, l = t & 63;
  const int ln31 = l & 31;

  const int b = blockIdx.x;
  const int h = b & 7, sid = b >> 3;
  const int n = sid >> 5;
  const int col0 = (sid & 31) * 128;

  // per-lane affine coeffs for its q column
  const int q = col0 + w*32 + ln31;
  float aq, bq;
  {
    float cm = -3.0e38f;
    #pragma unroll
    for (int hh = 0; hh < NQ0; ++hh)
      cm = fmaxf(cm, ws[OFF_CMAX + hh*(NB*HW) + n*HW + q]);
    const float i0 = 1.0f/(2.0f*(0.5f*(1.0f - cm) + kEPS));
    bq = i0 / kSIG; aq = (1.0f - i0) / kSIG;
  }

  const ushort* __restrict__ gAn = gA + (size_t)(n*128 + h*16)*8192;

  short8 pf[4];
  #pragma unroll
  for (int i = 0; i < 4; ++i)
    pf[i] = *(const short8*)(gAn + (size_t)(i*256 + t)*8);

  const int RB = (col0 >> 5) + w;
  short8 breg[16];
  #pragma unroll
  for (int kc = 0; kc < 16; ++kc)
    breg[kc] = *(const short8*)(gB +
        (((size_t)(n*128 + RB)*16 + kc) << 9) + l*8);

  float wsum = 0.f;

  for (int iter = 0; iter < 16; ++iter) {
    __syncthreads();
    #pragma unroll
    for (int i = 0; i < 4; ++i)
      *(short8*)&Ab[(i*256 + t)*8] = pf[i];
    __syncthreads();
    if (iter + 1 < 16) {
      const ushort* __restrict__ src = gAn + (size_t)(iter + 1)*8192;
      #pragma unroll
      for (int i = 0; i < 4; ++i)
        pf[i] = *(const short8*)(src + (size_t)(i*256 + t)*8);
    }

    f32x16 acc;
    #pragma unroll
    for (int e = 0; e < 16; ++e) acc[e] = 0.f;
    #pragma unroll
    for (int kc = 0; kc < 16; ++kc) {
      const short8 a0 = *(const short8*)&Ab[kc*512 + l*8];
      acc = __builtin_amdgcn_mfma_f32_32x32x16_bf16(a0, breg[kc], acc, 0, 0, 0);
    }
    #pragma unroll
    for (int r = 0; r < 16; ++r)
      wsum += __expf(fmaf(bq, acc[r], aq));
  }

  // lane l holds 16 of 32 rows; pair with l^32 for the full column sum
  wsum += __shfl_xor(wsum, 32, 64);
  if (l < 32) red2[w*32 + ln31] = wsum;
  __syncthreads();
  if (t < 128)
    ws[OFF_WSUM + h*(NB*HW) + n*HW + col0 + t] = red2[t];
}

// K5: gamma/beta arrays. grid = 64 (NB*HW/256).
__global__ __launch_bounds__(256) void k_gb9(float* __restrict__ ws) {
  const int idx = blockIdx.x*256 + threadIdx.x;   // n*HW + q
  float cm = -3.0e38f;
  #pragma unroll
  for (int hh = 0; hh < NQ0; ++hh)
    cm = fmaxf(cm, ws[OFF_CMAX + hh*(NB*HW) + idx]);
  const float inv2d = 1.0f/(2.0f*(0.5f*(1.0f - cm) + kEPS));
  const float beta  = inv2d / kSIG;
  const float alpha = (1.0f - inv2d) / kSIG;
  float sw = 0.f;
  #pragma unroll
  for (int hh = 0; hh < NQ0; ++hh)
    sw += ws[OFF_WSUM + hh*(NB*HW) + idx];
  ws[OFF_GB + idx]         = alpha - logf(sw + kEPS);  // gamma
  ws[OFF_GB + NB*HW + idx] = beta;
}

// K3c: GEMM sweep + row-max (maxv) partials via LDS transpose.
// Per iter: v = fmaf(beta_q, s, gamma_q) staged to Ef[32][132]; 256 threads
// reduce 32 rows x 128 q; thread group of 8 per row -> MAXP[cs][n][p].
__global__ __launch_bounds__(256, 4) void k_gC(
    const ushort* __restrict__ gA, const ushort* __restrict__ gB,
    float* __restrict__ ws)
{
  __shared__ ushort Ab[8192];
  __shared__ float Ef[32*132];

  const int t = threadIdx.x;
  const int w = t >> 6, l = t & 63;
  const int ln31 = l & 31, lhi = l >> 5;

  const int b = blockIdx.x;
  const int h = b & 7, sid = b >> 3;
  const int n = sid >> 5;
  const int cs = sid & 31;
  const int col0 = cs * 128;

  const int q = col0 + w*32 + ln31;
  const float gq = ws[OFF_GB + n*HW + q];
  const float bq = ws[OFF_GB + NB*HW + n*HW + q];

  const ushort* __restrict__ gAn = gA + (size_t)(n*128 + h*16)*8192;

  short8 pf[4];
  #pragma unroll
  for (int i = 0; i < 4; ++i)
    pf[i] = *(const short8*)(gAn + (size_t)(i*256 + t)*8);

  const int RB = (col0 >> 5) + w;
  short8 breg[16];
  #pragma unroll
  for (int kc = 0; kc < 16; ++kc)
    breg[kc] = *(const short8*)(gB +
        (((size_t)(n*128 + RB)*16 + kc) << 9) + l*8);

  const int ecol = w*32 + ln31;
  const int lr = t >> 3, qc = (t & 7) * 16;   // reduce assignment
  float* __restrict__ MAXP = ws + OFF_MAXP + (size_t)cs*(NB*HW) + n*HW;

  for (int iter = 0; iter < 16; ++iter) {
    __syncthreads();                 // prev MFMA Ab reads + prev Ef reads done
    #pragma unroll
    for (int i = 0; i < 4; ++i)
      *(short8*)&Ab[(i*256 + t)*8] = pf[i];
    __syncthreads();                 // Ab staged
    if (iter + 1 < 16) {
      const ushort* __restrict__ src = gAn + (size_t)(iter + 1)*8192;
      #pragma unroll
      for (int i = 0; i < 4; ++i)
        pf[i] = *(const short8*)(src + (size_t)(i*256 + t)*8);
    }

    f32x16 acc;
    #pragma unroll
    for (int e = 0; e < 16; ++e) acc[e] = 0.f;
    #pragma unroll
    for (int kc = 0; kc < 16; ++kc) {
      const short8 a0 = *(const short8*)&Ab[kc*512 + l*8];
      acc = __builtin_amdgcn_mfma_f32_32x32x16_bf16(a0, breg[kc], acc, 0, 0, 0);
    }

    #pragma unroll
    for (int r = 0; r < 16; ++r) {
      const int lrow = 4*lhi + (r & 3) + 8*(r >> 2);
      Ef[lrow*132 + ecol] = fmaf(bq, acc[r], gq);
    }
    __syncthreads();                 // Ef staged

    // row-max over 128 q: thread t handles row lr, 16-q chunk qc
    float m = -3.0e38f;
    #pragma unroll
    for (int k4 = 0; k4 < 4; ++k4) {
      const float4 v = *(const float4*)&Ef[lr*132 + qc + 4*k4];
      m = fmaxf(m, fmaxf(fmaxf(v.x, v.y), fmaxf(v.z, v.w)));
    }
    m = fmaxf(m, __shfl_xor(m, 1, 64));
    m = fmaxf(m, __shfl_xor(m, 2, 64));
    m = fmaxf(m, __shfl_xor(m, 4, 64));
    if ((t & 7) == 0) MAXP[h*512 + iter*32 + lr] = m;
  }
}

// K6: combine 32 col-strip maxima. grid = 64.
__global__ __launch_bounds__(256) void k_red(float* __restrict__ ws) {
  const int idx = blockIdx.x*256 + threadIdx.x;   // n*HW + p
  float m = ws[OFF_MAXP + idx];
  #pragma unroll
  for (int cs = 1; cs < NCS; ++cs)
    m = fmaxf(m, ws[OFF_MAXP + cs*(NB*HW) + idx]);
  ws[OFF_MAXV + idx] = m;
}

// K7: final loss. one block.
__global__ __launch_bounds__(256) void k_final9(const float* __restrict__ ws,
                                                float* __restrict__ out) {
  const int t = threadIdx.x;
  float loss = 0.f;
  for (int n = 0; n < NB; ++n) {
    float s = 0.f;
    for (int k = 0; k < 16; ++k)
      s += __expf(ws[OFF_MAXV + n*HW + k*256 + t]);
    const float tot = blockSum256(s);
    loss += -logf(tot*(1.0f/4096.0f) + kEPS);
  }
  if (t == 0) out[0] = loss*0.25f;
}

extern "C" void kernel_launch(void* const* d_in, const int* in_sizes, int n_in,
                              void* d_out, int out_size, void* d_ws, size_t ws_size,
                              hipStream_t stream) {
  const float* fT = (const float*)d_in[0];
  const float* fI = (const float*)d_in[1];
  float* out = (float*)d_out;
  float* ws  = (float*)d_ws;

  const size_t need_full = (size_t)WS_FLOATS_FULL * sizeof(float);
  if (ws_size < need_full) return;  // need ~20 MB now (was ~154 MB)

  const ushort* GT = (const ushort*)(ws + OFF_GT);
  const ushort* GI = (const ushort*)(ws + OFF_GI);
  k_mean9 <<<256,  256, 0, stream>>>(fT, ws);
  k_prep9 <<<1024, 256, 0, stream>>>(fT, fI, ws);
  k_gA    <<<1024, 256, 0, stream>>>(GT, GI, ws);   // colmax partials
  k_gB    <<<1024, 256, 0, stream>>>(GT, GI, ws);   // Wsum partials
  k_gb9   <<<64,   256, 0, stream>>>(ws);           // gamma/beta arrays
  k_gC    <<<1024, 256, 0, stream>>>(GT, GI, ws);   // maxv strip partials
  k_red   <<<64,   256, 0, stream>>>(ws);           // strip combine
  k_final9<<<1,    256, 0, stream>>>(ws, out);
}

// Round 5
// 197.222 us; speedup vs baseline: 1.0376x; 1.0376x over previous
//
#include <hip/hip_runtime.h>
#include <cmath>

// CXLoss pipeline, revision 23: 3 fused GEMM sweeps with K_B=2 (A-read reuse).
// R22 evidence: k_gC = 48.2us with WRITE=2MB -> the sweep LOOP costs 48us
// (stores were never the binder; R21's "write roofline" was wrong). Per
// block-iter the 4 waves issue 64 ds_read_b128 (same A data x4) vs 128 cyc of
// MFMA/SIMD: LDS read pipe ~5x oversubscribed. Fix: each wave holds TWO B
// col-tiles (breg[2][16], 128 VGPR) -> 2 MFMA per A-fragment read. Block
// covers 256 q-cols; grid 512 = 2 blocks/CU (launch_bounds(256,2)).

#define NB 4
#define CC 256
#define HW 4096
#define NQ0 8    // p-slab loop-split (CMAX/WSUM partials)
#define NCS 16   // q col-strips (MAXP partials)

static constexpr float kEPS = 1e-8f;
static constexpr float kSIG = 0.1f + 1e-8f;

typedef __attribute__((ext_vector_type(8)))  short short8;
typedef __attribute__((ext_vector_type(16))) float f32x16;

// workspace layout (float units)
enum {
  OFF_MEAN = 0,                        // 256 channel means
  OFF_CMAX = 256,                      // NQ0*NB*HW colmax partials
  OFF_WSUM = OFF_CMAX + NQ0*NB*HW,     // NQ0*NB*HW Wsum partials
  OFF_MAXP = OFF_WSUM + NQ0*NB*HW,     // NCS*NB*HW maxv partials (1MB)
  OFF_MAXV = OFF_MAXP + NCS*NB*HW,     // NB*HW maxv
  OFF_GB   = OFF_MAXV + NB*HW,         // gamma[NB*HW], beta[NB*HW]
  OFF_GT   = OFF_GB + 2*NB*HW,         // NB*HW*CC bf16, fragment-tiled
  OFF_GI   = OFF_GT + NB*HW*CC/2,
  WS_FLOATS_FULL = OFF_GI + NB*HW*CC/2
};

__device__ __forceinline__ ushort cvt_bf16(float x) {
  unsigned u = __float_as_uint(x);
  unsigned r = (u + 0x7fffu + ((u >> 16) & 1u)) >> 16;  // round-nearest-even
  return (ushort)r;
}
__device__ __forceinline__ float bf2f(ushort u) {
  return __uint_as_float((unsigned)u << 16);
}

__device__ __forceinline__ float blockSum256(float v) {
  __shared__ float sh[4];
  const int lane = threadIdx.x & 63, wv = threadIdx.x >> 6;
  #pragma unroll
  for (int o = 32; o > 0; o >>= 1) v += __shfl_down(v, o, 64);
  __syncthreads();
  if (lane == 0) sh[wv] = v;
  __syncthreads();
  return sh[0] + sh[1] + sh[2] + sh[3];
}

// K1: per-channel mean of featureT. grid=256
__global__ __launch_bounds__(256) void k_mean9(const float* __restrict__ fT,
                                               float* __restrict__ ws) {
  const int c = blockIdx.x, t = threadIdx.x;
  float s = 0.f;
  for (int n = 0; n < NB; ++n) {
    const float* p = fT + (size_t)(n*CC + c)*HW;
    #pragma unroll
    for (int k = 0; k < 16; ++k) s += p[k*256 + t];
  }
  const float tot = blockSum256(s);
  if (t == 0) ws[OFF_MEAN + c] = tot * (1.0f/16384.0f);
}

// K2: fused normalize + fragment-tiled bf16 write (verified R14 layout):
// offset_ushort(n, r32, kc) = ((n*128 + r32)*16 + kc)*512 + l*8
//   holds X[n][p = r32*32 + (l&31)][c = kc*16 + (l>>5)*8 + j], j<8.
// grid = 2 * NB * 128 = 1024 blocks.
__global__ __launch_bounds__(256) void k_prep9(const float* __restrict__ fT,
                                               const float* __restrict__ fI,
                                               float* __restrict__ ws) {
  __shared__ float stage[32][257];
  __shared__ float prt[8][32];
  __shared__ float sinv[32];
  const int t = threadIdx.x, l = t & 63;
  int bid = blockIdx.x;
  const int tensor = (bid >= 512); bid &= 511;
  const int n   = bid >> 7;
  const int r32 = bid & 127;
  const int p0  = r32 * 32;

  const float* __restrict__ src = tensor ? fI : fT;
  ushort* __restrict__ dst = (ushort*)(ws + (tensor ? OFF_GI : OFF_GT));
  const float* __restrict__ mean = ws + OFF_MEAN;

  const int pl = t & 31, cg = t >> 5;
  float acc = 0.f;
  #pragma unroll
  for (int i = 0; i < 32; ++i) {
    const int c = cg*32 + i;
    const float v = src[((size_t)(n*CC + c))*HW + p0 + pl] - mean[c];
    stage[pl][c] = v;
    acc += v*v;
  }
  prt[cg][pl] = acc;
  __syncthreads();
  if (t < 32) {
    float s = 0.f;
    #pragma unroll
    for (int g = 0; g < 8; ++g) s += prt[g][t];
    sinv[t] = 1.0f/(sqrtf(s) + kEPS);
  }
  __syncthreads();

  const int w = t >> 6, lhi = l >> 5, m = l & 31;
  const float iv = sinv[m];
  #pragma unroll
  for (int i = 0; i < 4; ++i) {
    const int kc = w*4 + i;
    const int cb = kc*16 + lhi*8;
    short8 o;
    #pragma unroll
    for (int j = 0; j < 8; ++j)
      ((ushort*)&o)[j] = cvt_bf16(stage[m][cb + j] * iv);
    *(short8*)(dst + (((size_t)(n*128 + r32)*16 + kc) << 9) + l*8) = o;
  }
}

// ---- shared sweep geometry (K_B=2) ----
// block b: h = b&7 (p-slab of 512), sid = b>>3; n = sid>>4, col0 = (sid&15)*256.
// wave w owns B col-tiles u in {0,1}: RB = (col0>>5) + u*4 + w,
//   lane's q_u = col0 + u*128 + w*32 + (l&31).
// per iter: Ab <- 32 p-rows; 16 kc: 1 ds_read_b128 -> 2 MFMA.
// C/D map: col(q) = lane&31, row(p) = (r&3) + 8*(r>>2) + 4*(lane>>5).

// K3a: GEMM sweep + colmax partials. grid 512, 2 blocks/CU.
__global__ __launch_bounds__(256, 2) void k_gA(
    const ushort* __restrict__ gA, const ushort* __restrict__ gB,
    float* __restrict__ ws)
{
  __shared__ ushort Ab[8192];
  __shared__ float red2[256];

  const int t = threadIdx.x;
  const int w = t >> 6, l = t & 63;
  const int ln31 = l & 31;

  const int b = blockIdx.x;
  const int h = b & 7, sid = b >> 3;
  const int n = sid >> 4;
  const int col0 = (sid & 15) * 256;

  const ushort* __restrict__ gAn = gA + (size_t)(n*128 + h*16)*8192;

  short8 pf[4];
  #pragma unroll
  for (int i = 0; i < 4; ++i)
    pf[i] = *(const short8*)(gAn + (size_t)(i*256 + t)*8);

  short8 breg0[16], breg1[16];
  {
    const int RB0 = (col0 >> 5) + w;
    const int RB1 = (col0 >> 5) + 4 + w;
    #pragma unroll
    for (int kc = 0; kc < 16; ++kc) {
      breg0[kc] = *(const short8*)(gB + (((size_t)(n*128 + RB0)*16 + kc) << 9) + l*8);
      breg1[kc] = *(const short8*)(gB + (((size_t)(n*128 + RB1)*16 + kc) << 9) + l*8);
    }
  }

  float run0 = -3.0e38f, run1 = -3.0e38f;

  for (int iter = 0; iter < 16; ++iter) {
    __syncthreads();
    #pragma unroll
    for (int i = 0; i < 4; ++i)
      *(short8*)&Ab[(i*256 + t)*8] = pf[i];
    __syncthreads();
    if (iter + 1 < 16) {
      const ushort* __restrict__ src = gAn + (size_t)(iter + 1)*8192;
      #pragma unroll
      for (int i = 0; i < 4; ++i)
        pf[i] = *(const short8*)(src + (size_t)(i*256 + t)*8);
    }

    f32x16 acc0, acc1;
    #pragma unroll
    for (int e = 0; e < 16; ++e) { acc0[e] = 0.f; acc1[e] = 0.f; }
    #pragma unroll
    for (int kc = 0; kc < 16; ++kc) {
      const short8 a0 = *(const short8*)&Ab[kc*512 + l*8];
      acc0 = __builtin_amdgcn_mfma_f32_32x32x16_bf16(a0, breg0[kc], acc0, 0, 0, 0);
      acc1 = __builtin_amdgcn_mfma_f32_32x32x16_bf16(a0, breg1[kc], acc1, 0, 0, 0);
    }
    #pragma unroll
    for (int r = 0; r < 16; ++r) {
      run0 = fmaxf(run0, acc0[r]);
      run1 = fmaxf(run1, acc1[r]);
    }
  }

  run0 = fmaxf(run0, __shfl_xor(run0, 32, 64));
  run1 = fmaxf(run1, __shfl_xor(run1, 32, 64));
  if (l < 32) {
    red2[w*32 + ln31]       = run0;
    red2[128 + w*32 + ln31] = run1;
  }
  __syncthreads();
  ws[OFF_CMAX + h*(NB*HW) + n*HW + col0 + t] = red2[t];
}

// K3b: GEMM sweep + Wsum partials. Per-lane a,b derived from CMAX.
__global__ __launch_bounds__(256, 2) void k_gB(
    const ushort* __restrict__ gA, const ushort* __restrict__ gB,
    float* __restrict__ ws)
{
  __shared__ ushort Ab[8192];
  __shared__ float red2[256];

  const int t = threadIdx.x;
  const int w = t >> 6, l = t & 63;
  const int ln31 = l & 31;

  const int b = blockIdx.x;
  const int h = b & 7, sid = b >> 3;
  const int n = sid >> 4;
  const int col0 = (sid & 15) * 256;

  // per-lane affine coeffs for both q columns
  float aq0, bq0, aq1, bq1;
  {
    const int q0 = col0 + w*32 + ln31;
    const int q1 = q0 + 128;
    float cm0 = -3.0e38f, cm1 = -3.0e38f;
    #pragma unroll
    for (int hh = 0; hh < NQ0; ++hh) {
      cm0 = fmaxf(cm0, ws[OFF_CMAX + hh*(NB*HW) + n*HW + q0]);
      cm1 = fmaxf(cm1, ws[OFF_CMAX + hh*(NB*HW) + n*HW + q1]);
    }
    const float i0 = 1.0f/(2.0f*(0.5f*(1.0f - cm0) + kEPS));
    const float i1 = 1.0f/(2.0f*(0.5f*(1.0f - cm1) + kEPS));
    bq0 = i0 / kSIG; aq0 = (1.0f - i0) / kSIG;
    bq1 = i1 / kSIG; aq1 = (1.0f - i1) / kSIG;
  }

  const ushort* __restrict__ gAn = gA + (size_t)(n*128 + h*16)*8192;

  short8 pf[4];
  #pragma unroll
  for (int i = 0; i < 4; ++i)
    pf[i] = *(const short8*)(gAn + (size_t)(i*256 + t)*8);

  short8 breg0[16], breg1[16];
  {
    const int RB0 = (col0 >> 5) + w;
    const int RB1 = (col0 >> 5) + 4 + w;
    #pragma unroll
    for (int kc = 0; kc < 16; ++kc) {
      breg0[kc] = *(const short8*)(gB + (((size_t)(n*128 + RB0)*16 + kc) << 9) + l*8);
      breg1[kc] = *(const short8*)(gB + (((size_t)(n*128 + RB1)*16 + kc) << 9) + l*8);
    }
  }

  float ws0 = 0.f, ws1 = 0.f;

  for (int iter = 0; iter < 16; ++iter) {
    __syncthreads();
    #pragma unroll
    for (int i = 0; i < 4; ++i)
      *(short8*)&Ab[(i*256 + t)*8] = pf[i];
    __syncthreads();
    if (iter + 1 < 16) {
      const ushort* __restrict__ src = gAn + (size_t)(iter + 1)*8192;
      #pragma unroll
      for (int i = 0; i < 4; ++i)
        pf[i] = *(const short8*)(src + (size_t)(i*256 + t)*8);
    }

    f32x16 acc0, acc1;
    #pragma unroll
    for (int e = 0; e < 16; ++e) { acc0[e] = 0.f; acc1[e] = 0.f; }
    #pragma unroll
    for (int kc = 0; kc < 16; ++kc) {
      const short8 a0 = *(const short8*)&Ab[kc*512 + l*8];
      acc0 = __builtin_amdgcn_mfma_f32_32x32x16_bf16(a0, breg0[kc], acc0, 0, 0, 0);
      acc1 = __builtin_amdgcn_mfma_f32_32x32x16_bf16(a0, breg1[kc], acc1, 0, 0, 0);
    }
    #pragma unroll
    for (int r = 0; r < 16; ++r) {
      ws0 += __expf(fmaf(bq0, acc0[r], aq0));
      ws1 += __expf(fmaf(bq1, acc1[r], aq1));
    }
  }

  // lane l holds 16 of 32 rows; pair with l^32 for the full column sum
  ws0 += __shfl_xor(ws0, 32, 64);
  ws1 += __shfl_xor(ws1, 32, 64);
  if (l < 32) {
    red2[w*32 + ln31]       = ws0;
    red2[128 + w*32 + ln31] = ws1;
  }
  __syncthreads();
  ws[OFF_WSUM + h*(NB*HW) + n*HW + col0 + t] = red2[t];
}

// K5: gamma/beta arrays. grid = 64 (NB*HW/256).
__global__ __launch_bounds__(256) void k_gb9(float* __restrict__ ws) {
  const int idx = blockIdx.x*256 + threadIdx.x;   // n*HW + q
  float cm = -3.0e38f;
  #pragma unroll
  for (int hh = 0; hh < NQ0; ++hh)
    cm = fmaxf(cm, ws[OFF_CMAX + hh*(NB*HW) + idx]);
  const float inv2d = 1.0f/(2.0f*(0.5f*(1.0f - cm) + kEPS));
  const float beta  = inv2d / kSIG;
  const float alpha = (1.0f - inv2d) / kSIG;
  float sw = 0.f;
  #pragma unroll
  for (int hh = 0; hh < NQ0; ++hh)
    sw += ws[OFF_WSUM + hh*(NB*HW) + idx];
  ws[OFF_GB + idx]         = alpha - logf(sw + kEPS);  // gamma
  ws[OFF_GB + NB*HW + idx] = beta;
}

// K3c: GEMM sweep + row-max (maxv) partials via LDS transpose.
// Per iter: v = fmaf(beta_q, s, gamma_q) staged to Ef[32][264]; 256 threads
// reduce 32 rows x 256 q (8 threads/row) -> MAXP[cs][n][p].
__global__ __launch_bounds__(256, 2) void k_gC(
    const ushort* __restrict__ gA, const ushort* __restrict__ gB,
    float* __restrict__ ws)
{
  __shared__ ushort Ab[8192];
  __shared__ float Ef[32*264];

  const int t = threadIdx.x;
  const int w = t >> 6, l = t & 63;
  const int ln31 = l & 31, lhi = l >> 5;

  const int b = blockIdx.x;
  const int h = b & 7, sid = b >> 3;
  const int n = sid >> 4;
  const int cs = sid & 15;
  const int col0 = cs * 256;

  float gq0, bq0, gq1, bq1;
  {
    const int q0 = col0 + w*32 + ln31;
    const int q1 = q0 + 128;
    gq0 = ws[OFF_GB + n*HW + q0];
    bq0 = ws[OFF_GB + NB*HW + n*HW + q0];
    gq1 = ws[OFF_GB + n*HW + q1];
    bq1 = ws[OFF_GB + NB*HW + n*HW + q1];
  }

  const ushort* __restrict__ gAn = gA + (size_t)(n*128 + h*16)*8192;

  short8 pf[4];
  #pragma unroll
  for (int i = 0; i < 4; ++i)
    pf[i] = *(const short8*)(gAn + (size_t)(i*256 + t)*8);

  short8 breg0[16], breg1[16];
  {
    const int RB0 = (col0 >> 5) + w;
    const int RB1 = (col0 >> 5) + 4 + w;
    #pragma unroll
    for (int kc = 0; kc < 16; ++kc) {
      breg0[kc] = *(const short8*)(gB + (((size_t)(n*128 + RB0)*16 + kc) << 9) + l*8);
      breg1[kc] = *(const short8*)(gB + (((size_t)(n*128 + RB1)*16 + kc) << 9) + l*8);
    }
  }

  const int ecol = w*32 + ln31;
  const int lr = t >> 3, qc = (t & 7) * 32;   // reduce assignment
  float* __restrict__ MAXP = ws + OFF_MAXP + (size_t)cs*(NB*HW) + n*HW;

  for (int iter = 0; iter < 16; ++iter) {
    __syncthreads();                 // prev MFMA Ab reads + prev Ef reads done
    #pragma unroll
    for (int i = 0; i < 4; ++i)
      *(short8*)&Ab[(i*256 + t)*8] = pf[i];
    __syncthreads();                 // Ab staged
    if (iter + 1 < 16) {
      const ushort* __restrict__ src = gAn + (size_t)(iter + 1)*8192;
      #pragma unroll
      for (int i = 0; i < 4; ++i)
        pf[i] = *(const short8*)(src + (size_t)(i*256 + t)*8);
    }

    f32x16 acc0, acc1;
    #pragma unroll
    for (int e = 0; e < 16; ++e) { acc0[e] = 0.f; acc1[e] = 0.f; }
    #pragma unroll
    for (int kc = 0; kc < 16; ++kc) {
      const short8 a0 = *(const short8*)&Ab[kc*512 + l*8];
      acc0 = __builtin_amdgcn_mfma_f32_32x32x16_bf16(a0, breg0[kc], acc0, 0, 0, 0);
      acc1 = __builtin_amdgcn_mfma_f32_32x32x16_bf16(a0, breg1[kc], acc1, 0, 0, 0);
    }

    #pragma unroll
    for (int r = 0; r < 16; ++r) {
      const int lrow = 4*lhi + (r & 3) + 8*(r >> 2);
      Ef[lrow*264 + ecol]       = fmaf(bq0, acc0[r], gq0);
      Ef[lrow*264 + 128 + ecol] = fmaf(bq1, acc1[r], gq1);
    }
    __syncthreads();                 // Ef staged

    // row-max over 256 q: thread t handles row lr, 32-q chunk qc
    float m = -3.0e38f;
    #pragma unroll
    for (int k4 = 0; k4 < 8; ++k4) {
      const float4 v = *(const float4*)&Ef[lr*264 + qc + 4*k4];
      m = fmaxf(m, fmaxf(fmaxf(v.x, v.y), fmaxf(v.z, v.w)));
    }
    m = fmaxf(m, __shfl_xor(m, 1, 64));
    m = fmaxf(m, __shfl_xor(m, 2, 64));
    m = fmaxf(m, __shfl_xor(m, 4, 64));
    if ((t & 7) == 0) MAXP[h*512 + iter*32 + lr] = m;
  }
}

// K6: combine 16 col-strip maxima. grid = 64.
__global__ __launch_bounds__(256) void k_red(float* __restrict__ ws) {
  const int idx = blockIdx.x*256 + threadIdx.x;   // n*HW + p
  float m = ws[OFF_MAXP + idx];
  #pragma unroll
  for (int cs = 1; cs < NCS; ++cs)
    m = fmaxf(m, ws[OFF_MAXP + cs*(NB*HW) + idx]);
  ws[OFF_MAXV + idx] = m;
}

// K7: final loss. one block.
__global__ __launch_bounds__(256) void k_final9(const float* __restrict__ ws,
                                                float* __restrict__ out) {
  const int t = threadIdx.x;
  float loss = 0.f;
  for (int n = 0; n < NB; ++n) {
    float s = 0.f;
    for (int k = 0; k < 16; ++k)
      s += __expf(ws[OFF_MAXV + n*HW + k*256 + t]);
    const float tot = blockSum256(s);
    loss += -logf(tot*(1.0f/4096.0f) + kEPS);
  }
  if (t == 0) out[0] = loss*0.25f;
}

extern "C" void kernel_launch(void* const* d_in, const int* in_sizes, int n_in,
                              void* d_out, int out_size, void* d_ws, size_t ws_size,
                              hipStream_t stream) {
  const float* fT = (const float*)d_in[0];
  const float* fI = (const float*)d_in[1];
  float* out = (float*)d_out;
  float* ws  = (float*)d_ws;

  const size_t need_full = (size_t)WS_FLOATS_FULL * sizeof(float);
  if (ws_size < need_full) return;  // ~19 MB

  const ushort* GT = (const ushort*)(ws + OFF_GT);
  const ushort* GI = (const ushort*)(ws + OFF_GI);
  k_mean9 <<<256,  256, 0, stream>>>(fT, ws);
  k_prep9 <<<1024, 256, 0, stream>>>(fT, fI, ws);
  k_gA    <<<512,  256, 0, stream>>>(GT, GI, ws);   // colmax partials
  k_gB    <<<512,  256, 0, stream>>>(GT, GI, ws);   // Wsum partials
  k_gb9   <<<64,   256, 0, stream>>>(ws);           // gamma/beta arrays
  k_gC    <<<512,  256, 0, stream>>>(GT, GI, ws);   // maxv strip partials
  k_red   <<<64,   256, 0, stream>>>(ws);           // strip combine
  k_final9<<<1,    256, 0, stream>>>(ws, out);
}

// Round 6
// 182.358 us; speedup vs baseline: 1.1222x; 1.0815x over previous
//
#include <hip/hip_runtime.h>
#include <cmath>

// CXLoss pipeline, revision 24: 3 GEMM sweeps with async staging.
// R23 evidence: K_B=2 gave 48.2->44.7us only; 3350 cyc/block-iter vs ~256 cyc
// MFMA content => latency-bound on pf->LDS staging + vmcnt(0) barrier drains
// (the documented m97-structure stall), not LDS throughput. Fix (T3/T4-lite):
//  - global_load_lds width=16 for A (layout is wave-uniform base + lane*16)
//  - Ab[2] double buffer, raw s_barrier, counted s_waitcnt vmcnt(4) --
//    prefetch stays in flight across barriers; lgkmcnt(0) guards WAW reuse
//  - XCD-affinity remap: 8 h-slabs sharing a B-panel colocate per XCD
//  - k_gb9 folded into k_gC prologue (bit-identical formula)

#define NB 4
#define CC 256
#define HW 4096
#define NQ0 8    // p-slab loop-split (CMAX/WSUM partials)
#define NCS 16   // q col-strips (MAXP partials)

static constexpr float kEPS = 1e-8f;
static constexpr float kSIG = 0.1f + 1e-8f;

typedef __attribute__((ext_vector_type(8)))  short short8;
typedef __attribute__((ext_vector_type(16))) float f32x16;

// workspace layout (float units)
enum {
  OFF_MEAN = 0,                        // 256 channel means
  OFF_CMAX = 256,                      // NQ0*NB*HW colmax partials
  OFF_WSUM = OFF_CMAX + NQ0*NB*HW,     // NQ0*NB*HW Wsum partials
  OFF_MAXP = OFF_WSUM + NQ0*NB*HW,     // NCS*NB*HW maxv partials (1MB)
  OFF_MAXV = OFF_MAXP + NCS*NB*HW,     // NB*HW maxv
  OFF_GT   = OFF_MAXV + NB*HW,         // NB*HW*CC bf16, fragment-tiled
  OFF_GI   = OFF_GT + NB*HW*CC/2,
  WS_FLOATS_FULL = OFF_GI + NB*HW*CC/2
};

__device__ __forceinline__ ushort cvt_bf16(float x) {
  unsigned u = __float_as_uint(x);
  unsigned r = (u + 0x7fffu + ((u >> 16) & 1u)) >> 16;  // round-nearest-even
  return (ushort)r;
}

__device__ __forceinline__ void glds16(const ushort* g, ushort* l) {
  __builtin_amdgcn_global_load_lds(
      (const __attribute__((address_space(1))) unsigned*)g,
      (__attribute__((address_space(3))) unsigned*)l, 16, 0, 0);
}
__device__ __forceinline__ void s_bar()  { asm volatile("s_barrier" ::: "memory"); }
__device__ __forceinline__ void w_vm4()  { asm volatile("s_waitcnt vmcnt(4)" ::: "memory"); }
__device__ __forceinline__ void w_vm0()  { asm volatile("s_waitcnt vmcnt(0)" ::: "memory"); }
__device__ __forceinline__ void w_lgkm() { asm volatile("s_waitcnt lgkmcnt(0)" ::: "memory"); }

__device__ __forceinline__ float blockSum256(float v) {
  __shared__ float sh[4];
  const int lane = threadIdx.x & 63, wv = threadIdx.x >> 6;
  #pragma unroll
  for (int o = 32; o > 0; o >>= 1) v += __shfl_down(v, o, 64);
  __syncthreads();
  if (lane == 0) sh[wv] = v;
  __syncthreads();
  return sh[0] + sh[1] + sh[2] + sh[3];
}

// K1: per-channel mean of featureT. grid=256
__global__ __launch_bounds__(256) void k_mean9(const float* __restrict__ fT,
                                               float* __restrict__ ws) {
  const int c = blockIdx.x, t = threadIdx.x;
  float s = 0.f;
  for (int n = 0; n < NB; ++n) {
    const float* p = fT + (size_t)(n*CC + c)*HW;
    #pragma unroll
    for (int k = 0; k < 16; ++k) s += p[k*256 + t];
  }
  const float tot = blockSum256(s);
  if (t == 0) ws[OFF_MEAN + c] = tot * (1.0f/16384.0f);
}

// K2: fused normalize + fragment-tiled bf16 write (verified R14 layout):
// offset_ushort(n, r32, kc) = ((n*128 + r32)*16 + kc)*512 + l*8
//   holds X[n][p = r32*32 + (l&31)][c = kc*16 + (l>>5)*8 + j], j<8.
// grid = 2 * NB * 128 = 1024 blocks.
__global__ __launch_bounds__(256) void k_prep9(const float* __restrict__ fT,
                                               const float* __restrict__ fI,
                                               float* __restrict__ ws) {
  __shared__ float stage[32][257];
  __shared__ float prt[8][32];
  __shared__ float sinv[32];
  const int t = threadIdx.x, l = t & 63;
  int bid = blockIdx.x;
  const int tensor = (bid >= 512); bid &= 511;
  const int n   = bid >> 7;
  const int r32 = bid & 127;
  const int p0  = r32 * 32;

  const float* __restrict__ src = tensor ? fI : fT;
  ushort* __restrict__ dst = (ushort*)(ws + (tensor ? OFF_GI : OFF_GT));
  const float* __restrict__ mean = ws + OFF_MEAN;

  const int pl = t & 31, cg = t >> 5;
  float acc = 0.f;
  #pragma unroll
  for (int i = 0; i < 32; ++i) {
    const int c = cg*32 + i;
    const float v = src[((size_t)(n*CC + c))*HW + p0 + pl] - mean[c];
    stage[pl][c] = v;
    acc += v*v;
  }
  prt[cg][pl] = acc;
  __syncthreads();
  if (t < 32) {
    float s = 0.f;
    #pragma unroll
    for (int g = 0; g < 8; ++g) s += prt[g][t];
    sinv[t] = 1.0f/(sqrtf(s) + kEPS);
  }
  __syncthreads();

  const int w = t >> 6, lhi = l >> 5, m = l & 31;
  const float iv = sinv[m];
  #pragma unroll
  for (int i = 0; i < 4; ++i) {
    const int kc = w*4 + i;
    const int cb = kc*16 + lhi*8;
    short8 o;
    #pragma unroll
    for (int j = 0; j < 8; ++j)
      ((ushort*)&o)[j] = cvt_bf16(stage[m][cb + j] * iv);
    *(short8*)(dst + (((size_t)(n*128 + r32)*16 + kc) << 9) + l*8) = o;
  }
}

// ---- shared sweep geometry (K_B=2, async staging) ----
// launched L: xcd = L&7, j = L>>3; sid = xcd*8 + (j&7); h = j>>3.
// n = sid>>4, col0 = (sid&15)*256.  (8 h-blocks of one sid share one XCD.)
// per iter: glds tile(iter) -> Ab[iter&1]; 16 kc: 1 ds_read_b128 -> 2 MFMA.
// C/D map: col(q) = lane&31, row(p) = (r&3) + 8*(r>>2) + 4*(lane>>5).

// K3a: GEMM sweep + colmax partials. grid 512.
__global__ __launch_bounds__(256, 2) void k_gA(
    const ushort* __restrict__ gA, const ushort* __restrict__ gB,
    float* __restrict__ ws)
{
  __shared__ ushort Ab[2][8192];
  __shared__ float red2[256];

  const int t = threadIdx.x;
  const int w = t >> 6, l = t & 63;
  const int ln31 = l & 31;

  const int L = blockIdx.x;
  const int xcd = L & 7, j = L >> 3;
  const int sid = xcd*8 + (j & 7);
  const int h   = j >> 3;
  const int n = sid >> 4;
  const int col0 = (sid & 15) * 256;

  const ushort* __restrict__ gAn = gA + (size_t)(n*128 + h*16)*8192;

  // prologue: async-stage tiles 0,1
  #pragma unroll
  for (int i = 0; i < 4; ++i)
    glds16(gAn + (size_t)(i*256 + t)*8, &Ab[0][(i*256 + t)*8]);
  #pragma unroll
  for (int i = 0; i < 4; ++i)
    glds16(gAn + 8192 + (size_t)(i*256 + t)*8, &Ab[1][(i*256 + t)*8]);

  short8 breg0[16], breg1[16];
  {
    const int RB0 = (col0 >> 5) + w;
    const int RB1 = (col0 >> 5) + 4 + w;
    #pragma unroll
    for (int kc = 0; kc < 16; ++kc) {
      breg0[kc] = *(const short8*)(gB + (((size_t)(n*128 + RB0)*16 + kc) << 9) + l*8);
      breg1[kc] = *(const short8*)(gB + (((size_t)(n*128 + RB1)*16 + kc) << 9) + l*8);
    }
  }

  float run0 = -3.0e38f, run1 = -3.0e38f;

  for (int iter = 0; iter < 16; ++iter) {
    if (iter < 15) w_vm4(); else w_vm0();
    s_bar();                                   // Ab[iter&1] staged (all waves)

    const ushort* __restrict__ Abuf = &Ab[iter & 1][0];
    f32x16 acc0, acc1;
    #pragma unroll
    for (int e = 0; e < 16; ++e) { acc0[e] = 0.f; acc1[e] = 0.f; }
    #pragma unroll
    for (int kc = 0; kc < 16; ++kc) {
      const short8 a0 = *(const short8*)&Abuf[kc*512 + l*8];
      acc0 = __builtin_amdgcn_mfma_f32_32x32x16_bf16(a0, breg0[kc], acc0, 0, 0, 0);
      acc1 = __builtin_amdgcn_mfma_f32_32x32x16_bf16(a0, breg1[kc], acc1, 0, 0, 0);
    }
    w_lgkm();
    s_bar();                                   // all waves done reading Ab[iter&1]
    if (iter + 2 < 16) {
      const ushort* __restrict__ src = gAn + (size_t)(iter + 2)*8192;
      ushort* __restrict__ dstl = &Ab[iter & 1][0];
      #pragma unroll
      for (int i = 0; i < 4; ++i)
        glds16(src + (size_t)(i*256 + t)*8, dstl + (i*256 + t)*8);
    }

    #pragma unroll
    for (int r = 0; r < 16; ++r) {
      run0 = fmaxf(run0, acc0[r]);
      run1 = fmaxf(run1, acc1[r]);
    }
  }

  run0 = fmaxf(run0, __shfl_xor(run0, 32, 64));
  run1 = fmaxf(run1, __shfl_xor(run1, 32, 64));
  if (l < 32) {
    red2[w*32 + ln31]       = run0;
    red2[128 + w*32 + ln31] = run1;
  }
  __syncthreads();
  ws[OFF_CMAX + h*(NB*HW) + n*HW + col0 + t] = red2[t];
}

// K3b: GEMM sweep + Wsum partials. Per-lane a,b derived from CMAX.
__global__ __launch_bounds__(256, 2) void k_gB(
    const ushort* __restrict__ gA, const ushort* __restrict__ gB,
    float* __restrict__ ws)
{
  __shared__ ushort Ab[2][8192];
  __shared__ float red2[256];

  const int t = threadIdx.x;
  const int w = t >> 6, l = t & 63;
  const int ln31 = l & 31;

  const int L = blockIdx.x;
  const int xcd = L & 7, j = L >> 3;
  const int sid = xcd*8 + (j & 7);
  const int h   = j >> 3;
  const int n = sid >> 4;
  const int col0 = (sid & 15) * 256;

  const ushort* __restrict__ gAn = gA + (size_t)(n*128 + h*16)*8192;

  #pragma unroll
  for (int i = 0; i < 4; ++i)
    glds16(gAn + (size_t)(i*256 + t)*8, &Ab[0][(i*256 + t)*8]);
  #pragma unroll
  for (int i = 0; i < 4; ++i)
    glds16(gAn + 8192 + (size_t)(i*256 + t)*8, &Ab[1][(i*256 + t)*8]);

  // per-lane affine coeffs for both q columns (same order as R23)
  float aq0, bq0, aq1, bq1;
  {
    const int q0 = col0 + w*32 + ln31;
    const int q1 = q0 + 128;
    float cm0 = -3.0e38f, cm1 = -3.0e38f;
    #pragma unroll
    for (int hh = 0; hh < NQ0; ++hh) {
      cm0 = fmaxf(cm0, ws[OFF_CMAX + hh*(NB*HW) + n*HW + q0]);
      cm1 = fmaxf(cm1, ws[OFF_CMAX + hh*(NB*HW) + n*HW + q1]);
    }
    const float i0 = 1.0f/(2.0f*(0.5f*(1.0f - cm0) + kEPS));
    const float i1 = 1.0f/(2.0f*(0.5f*(1.0f - cm1) + kEPS));
    bq0 = i0 / kSIG; aq0 = (1.0f - i0) / kSIG;
    bq1 = i1 / kSIG; aq1 = (1.0f - i1) / kSIG;
  }

  short8 breg0[16], breg1[16];
  {
    const int RB0 = (col0 >> 5) + w;
    const int RB1 = (col0 >> 5) + 4 + w;
    #pragma unroll
    for (int kc = 0; kc < 16; ++kc) {
      breg0[kc] = *(const short8*)(gB + (((size_t)(n*128 + RB0)*16 + kc) << 9) + l*8);
      breg1[kc] = *(const short8*)(gB + (((size_t)(n*128 + RB1)*16 + kc) << 9) + l*8);
    }
  }

  float ws0 = 0.f, ws1 = 0.f;

  for (int iter = 0; iter < 16; ++iter) {
    if (iter < 15) w_vm4(); else w_vm0();
    s_bar();

    const ushort* __restrict__ Abuf = &Ab[iter & 1][0];
    f32x16 acc0, acc1;
    #pragma unroll
    for (int e = 0; e < 16; ++e) { acc0[e] = 0.f; acc1[e] = 0.f; }
    #pragma unroll
    for (int kc = 0; kc < 16; ++kc) {
      const short8 a0 = *(const short8*)&Abuf[kc*512 + l*8];
      acc0 = __builtin_amdgcn_mfma_f32_32x32x16_bf16(a0, breg0[kc], acc0, 0, 0, 0);
      acc1 = __builtin_amdgcn_mfma_f32_32x32x16_bf16(a0, breg1[kc], acc1, 0, 0, 0);
    }
    w_lgkm();
    s_bar();
    if (iter + 2 < 16) {
      const ushort* __restrict__ src = gAn + (size_t)(iter + 2)*8192;
      ushort* __restrict__ dstl = &Ab[iter & 1][0];
      #pragma unroll
      for (int i = 0; i < 4; ++i)
        glds16(src + (size_t)(i*256 + t)*8, dstl + (i*256 + t)*8);
    }

    #pragma unroll
    for (int r = 0; r < 16; ++r) {
      ws0 += __expf(fmaf(bq0, acc0[r], aq0));
      ws1 += __expf(fmaf(bq1, acc1[r], aq1));
    }
  }

  ws0 += __shfl_xor(ws0, 32, 64);
  ws1 += __shfl_xor(ws1, 32, 64);
  if (l < 32) {
    red2[w*32 + ln31]       = ws0;
    red2[128 + w*32 + ln31] = ws1;
  }
  __syncthreads();
  ws[OFF_WSUM + h*(NB*HW) + n*HW + col0 + t] = red2[t];
}

// K3c: GEMM sweep + row-max (maxv) partials via LDS transpose.
// gamma/beta computed per-block in prologue (bit-identical to old k_gb9).
__global__ __launch_bounds__(256, 2) void k_gC(
    const ushort* __restrict__ gA, const ushort* __restrict__ gB,
    float* __restrict__ ws)
{
  __shared__ ushort Ab[2][8192];
  __shared__ float Ef[32*264];
  __shared__ float gam[256], bet[256];

  const int t = threadIdx.x;
  const int w = t >> 6, l = t & 63;
  const int ln31 = l & 31, lhi = l >> 5;

  const int L = blockIdx.x;
  const int xcd = L & 7, j = L >> 3;
  const int sid = xcd*8 + (j & 7);
  const int h   = j >> 3;
  const int n = sid >> 4;
  const int cs = sid & 15;
  const int col0 = cs * 256;

  // gamma/beta for this block's 256 q (formula/order == old k_gb9)
  {
    const int idx = n*HW + col0 + t;
    float cm = -3.0e38f;
    #pragma unroll
    for (int hh = 0; hh < NQ0; ++hh)
      cm = fmaxf(cm, ws[OFF_CMAX + hh*(NB*HW) + idx]);
    const float inv2d = 1.0f/(2.0f*(0.5f*(1.0f - cm) + kEPS));
    const float beta  = inv2d / kSIG;
    const float alpha = (1.0f - inv2d) / kSIG;
    float sw = 0.f;
    #pragma unroll
    for (int hh = 0; hh < NQ0; ++hh)
      sw += ws[OFF_WSUM + hh*(NB*HW) + idx];
    gam[t] = alpha - logf(sw + kEPS);
    bet[t] = beta;
  }
  __syncthreads();

  const float gq0 = gam[w*32 + ln31],       bq0 = bet[w*32 + ln31];
  const float gq1 = gam[128 + w*32 + ln31], bq1 = bet[128 + w*32 + ln31];

  const ushort* __restrict__ gAn = gA + (size_t)(n*128 + h*16)*8192;

  #pragma unroll
  for (int i = 0; i < 4; ++i)
    glds16(gAn + (size_t)(i*256 + t)*8, &Ab[0][(i*256 + t)*8]);
  #pragma unroll
  for (int i = 0; i < 4; ++i)
    glds16(gAn + 8192 + (size_t)(i*256 + t)*8, &Ab[1][(i*256 + t)*8]);

  short8 breg0[16], breg1[16];
  {
    const int RB0 = (col0 >> 5) + w;
    const int RB1 = (col0 >> 5) + 4 + w;
    #pragma unroll
    for (int kc = 0; kc < 16; ++kc) {
      breg0[kc] = *(const short8*)(gB + (((size_t)(n*128 + RB0)*16 + kc) << 9) + l*8);
      breg1[kc] = *(const short8*)(gB + (((size_t)(n*128 + RB1)*16 + kc) << 9) + l*8);
    }
  }

  const int ecol = w*32 + ln31;
  const int lr = t >> 3, qc = (t & 7) * 32;
  float* __restrict__ MAXP = ws + OFF_MAXP + (size_t)cs*(NB*HW) + n*HW;

  for (int iter = 0; iter < 16; ++iter) {
    if (iter < 15) w_vm4(); else w_vm0();
    w_lgkm();                                  // prev-iter Ef reads drained
    s_bar();                                   // Ab[iter&1] staged; Ef reusable

    const ushort* __restrict__ Abuf = &Ab[iter & 1][0];
    f32x16 acc0, acc1;
    #pragma unroll
    for (int e = 0; e < 16; ++e) { acc0[e] = 0.f; acc1[e] = 0.f; }
    #pragma unroll
    for (int kc = 0; kc < 16; ++kc) {
      const short8 a0 = *(const short8*)&Abuf[kc*512 + l*8];
      acc0 = __builtin_amdgcn_mfma_f32_32x32x16_bf16(a0, breg0[kc], acc0, 0, 0, 0);
      acc1 = __builtin_amdgcn_mfma_f32_32x32x16_bf16(a0, breg1[kc], acc1, 0, 0, 0);
    }

    #pragma unroll
    for (int r = 0; r < 16; ++r) {
      const int lrow = 4*lhi + (r & 3) + 8*(r >> 2);
      Ef[lrow*264 + ecol]       = fmaf(bq0, acc0[r], gq0);
      Ef[lrow*264 + 128 + ecol] = fmaf(bq1, acc1[r], gq1);
    }
    w_lgkm();
    s_bar();                                   // A reads done + Ef staged
    if (iter + 2 < 16) {
      const ushort* __restrict__ src = gAn + (size_t)(iter + 2)*8192;
      ushort* __restrict__ dstl = &Ab[iter & 1][0];
      #pragma unroll
      for (int i = 0; i < 4; ++i)
        glds16(src + (size_t)(i*256 + t)*8, dstl + (i*256 + t)*8);
    }

    // row-max over 256 q: thread t handles row lr, 32-q chunk qc
    float m = -3.0e38f;
    #pragma unroll
    for (int k4 = 0; k4 < 8; ++k4) {
      const float4 v = *(const float4*)&Ef[lr*264 + qc + 4*k4];
      m = fmaxf(m, fmaxf(fmaxf(v.x, v.y), fmaxf(v.z, v.w)));
    }
    m = fmaxf(m, __shfl_xor(m, 1, 64));
    m = fmaxf(m, __shfl_xor(m, 2, 64));
    m = fmaxf(m, __shfl_xor(m, 4, 64));
    if ((t & 7) == 0) MAXP[h*512 + iter*32 + lr] = m;
  }
}

// K6: combine 16 col-strip maxima. grid = 64.
__global__ __launch_bounds__(256) void k_red(float* __restrict__ ws) {
  const int idx = blockIdx.x*256 + threadIdx.x;   // n*HW + p
  float m = ws[OFF_MAXP + idx];
  #pragma unroll
  for (int cs = 1; cs < NCS; ++cs)
    m = fmaxf(m, ws[OFF_MAXP + cs*(NB*HW) + idx]);
  ws[OFF_MAXV + idx] = m;
}

// K7: final loss. one block.
__global__ __launch_bounds__(256) void k_final9(const float* __restrict__ ws,
                                                float* __restrict__ out) {
  const int t = threadIdx.x;
  float loss = 0.f;
  for (int n = 0; n < NB; ++n) {
    float s = 0.f;
    for (int k = 0; k < 16; ++k)
      s += __expf(ws[OFF_MAXV + n*HW + k*256 + t]);
    const float tot = blockSum256(s);
    loss += -logf(tot*(1.0f/4096.0f) + kEPS);
  }
  if (t == 0) out[0] = loss*0.25f;
}

extern "C" void kernel_launch(void* const* d_in, const int* in_sizes, int n_in,
                              void* d_out, int out_size, void* d_ws, size_t ws_size,
                              hipStream_t stream) {
  const float* fT = (const float*)d_in[0];
  const float* fI = (const float*)d_in[1];
  float* out = (float*)d_out;
  float* ws  = (float*)d_ws;

  const size_t need_full = (size_t)WS_FLOATS_FULL * sizeof(float);
  if (ws_size < need_full) return;  // ~19 MB

  const ushort* GT = (const ushort*)(ws + OFF_GT);
  const ushort* GI = (const ushort*)(ws + OFF_GI);
  k_mean9 <<<256,  256, 0, stream>>>(fT, ws);
  k_prep9 <<<1024, 256, 0, stream>>>(fT, fI, ws);
  k_gA    <<<512,  256, 0, stream>>>(GT, GI, ws);   // colmax partials
  k_gB    <<<512,  256, 0, stream>>>(GT, GI, ws);   // Wsum partials
  k_gC    <<<512,  256, 0, stream>>>(GT, GI, ws);   // maxv strip partials
  k_red   <<<64,   256, 0, stream>>>(ws);           // strip combine
  k_final9<<<1,    256, 0, stream>>>(ws, out);
}